// Round 3
// baseline (203.597 us; speedup 1.0000x reference)
//
#include <hip/hip_runtime.h>
#include <stdint.h>

#define Bn 4
#define Cn 64
#define Sn 4096
#define Gn 32

typedef float v4f __attribute__((ext_vector_type(4)));
typedef short v8s __attribute__((ext_vector_type(8)));

#define MFMA16(a,b,c) __builtin_amdgcn_mfma_f32_16x16x32_bf16((a),(b),(c),0,0,0)

__device__ __forceinline__ float bf2f(uint16_t u){
  union { uint32_t i; float f; } x; x.i = ((uint32_t)u) << 16; return x.f;
}
__device__ __forceinline__ uint16_t f2bf(float f){
  union { float f; uint32_t i; } x; x.f = f;
  uint32_t r = x.i + 0x7fffu + ((x.i >> 16) & 1u);
  return (uint16_t)(r >> 16);
}
__device__ __forceinline__ v8s pack8(float4 a, float4 b){
  v8s r;
  r[0]=(short)f2bf(a.x); r[1]=(short)f2bf(a.y); r[2]=(short)f2bf(a.z); r[3]=(short)f2bf(a.w);
  r[4]=(short)f2bf(b.x); r[5]=(short)f2bf(b.y); r[6]=(short)f2bf(b.z); r[7]=(short)f2bf(b.w);
  return r;
}

// ---------------- kernel 1: GroupNorm stats (mean, rstd) ----------------
// grid 128 = b*32+g ; each block reduces 2 channels x 4096 spatial = 8192 contiguous fp32
__global__ __launch_bounds__(256) void gn_stats(const float* __restrict__ x,
                                                float* __restrict__ stats)
{
  const int tid = threadIdx.x;
  const float* base = x + (size_t)blockIdx.x * 8192;
  float sum = 0.f, sq = 0.f;
  #pragma unroll
  for (int i = 0; i < 8; ++i) {
    float4 v = *(const float4*)(base + ((i << 8) + tid)*4);
    sum += v.x + v.y + v.z + v.w;
    sq  += v.x*v.x + v.y*v.y + v.z*v.z + v.w*v.w;
  }
  #pragma unroll
  for (int off = 1; off < 64; off <<= 1) {
    sum += __shfl_xor(sum, off);
    sq  += __shfl_xor(sq, off);
  }
  __shared__ float red[8];
  const int w = tid >> 6;
  if ((tid & 63) == 0) { red[w] = sum; red[4+w] = sq; }
  __syncthreads();
  if (tid == 0) {
    float s = red[0]+red[1]+red[2]+red[3];
    float q = red[4]+red[5]+red[6]+red[7];
    float mean = s * (1.f/8192.f);
    float var  = q * (1.f/8192.f) - mean*mean;
    stats[blockIdx.x]       = mean;
    stats[128 + blockIdx.x] = rsqrtf(fmaxf(var, 0.f) + 1e-5f);
  }
}

// ---------------- kernel 2: normalize + QKV projection ----------------
// grid 256 = b*64 + s_tile ; Q,K out [b][s][c] bf16, V out [b][c][s] bf16
__global__ __launch_bounds__(256) void gn_qkv(
    const float* __restrict__ xg, const float* __restrict__ gamma,
    const float* __restrict__ beta,
    const float* __restrict__ wq, const float* __restrict__ bq,
    const float* __restrict__ wk, const float* __restrict__ bk,
    const float* __restrict__ wv, const float* __restrict__ bv,
    const float* __restrict__ stats,
    uint16_t* __restrict__ Qg, uint16_t* __restrict__ Kg, uint16_t* __restrict__ Vg)
{
  __shared__ uint16_t Hs[64*72];   // [s][c] bf16, pad 72
  const int tid  = threadIdx.x;
  const int w    = tid >> 6;
  const int lane = tid & 63;
  const int l15  = lane & 15;
  const int quad = lane >> 4;
  const int b      = blockIdx.x >> 6;
  const int s_base = (blockIdx.x & 63) << 6;

  { // thread owns channel c = lane, 16 spatial rows from its wave
    const int c = lane;
    const int g = c >> 1;
    const float mean = stats[b*Gn + g];
    const float rstd = stats[128 + b*Gn + g];
    const float ga = gamma[c], be = beta[c];
    const float* xr = xg + ((size_t)b*Cn + c)*Sn + s_base + (w << 4);
    #pragma unroll
    for (int j = 0; j < 16; j += 4) {
      float4 v = *(const float4*)(xr + j);
      const int srow = (w << 4) + j;
      Hs[(srow+0)*72 + c] = f2bf((v.x - mean)*rstd*ga + be);
      Hs[(srow+1)*72 + c] = f2bf((v.y - mean)*rstd*ga + be);
      Hs[(srow+2)*72 + c] = f2bf((v.z - mean)*rstd*ga + be);
      Hs[(srow+3)*72 + c] = f2bf((v.w - mean)*rstd*ga + be);
    }
  }
  __syncthreads();

  // B fragments: n = spatial col (wave owns 16 cols), k = channel
  const int brow = (w << 4) + l15;
  v8s bh0 = *(const v8s*)(Hs + brow*72 + (quad << 3));
  v8s bh1 = *(const v8s*)(Hs + brow*72 + 32 + (quad << 3));

  const float* Ws[3] = {wq, wk, wv};
  const float* Bs[3] = {bq, bk, bv};
  #pragma unroll
  for (int ot = 0; ot < 12; ++ot) {
    const int wsel = ot >> 2;
    const int o16  = (ot & 3) << 4;
    const float* Wr = Ws[wsel] + (o16 + l15)*64 + (quad << 3);
    v8s a0 = pack8(*(const float4*)(Wr),      *(const float4*)(Wr + 4));
    v8s a1 = pack8(*(const float4*)(Wr + 32), *(const float4*)(Wr + 36));
    v4f d = (v4f){0.f,0.f,0.f,0.f};
    d = MFMA16(a0, bh0, d);
    d = MFMA16(a1, bh1, d);
    const int s = s_base + (w << 4) + l15;
    #pragma unroll
    for (int r = 0; r < 4; ++r) {
      const int o = o16 + (quad << 2) + r;
      const float val = d[r] + Bs[wsel][o];
      if (wsel == 0)      Qg[((size_t)b*Sn + s)*64 + o] = f2bf(val);
      else if (wsel == 1) Kg[((size_t)b*Sn + s)*64 + o] = f2bf(val);
      else                Vg[((size_t)b*Cn + o)*Sn + s] = f2bf(val);
    }
  }
}

// ---------------- kernel 3: flash attention (all-bf16 internal) ----------------
// grid 256 = b*64 + q_tile(64 rows); 4 waves x 16 rows; 64 tiles of 64 keys
__global__ __launch_bounds__(256) void attn_flash(
    const uint16_t* __restrict__ Qg, const uint16_t* __restrict__ Kg,
    const uint16_t* __restrict__ Vg, uint16_t* __restrict__ Og)
{
  __shared__ uint16_t Qs[64*72];       // [i][c]
  __shared__ uint16_t Ks[64*72];       // [j][c]
  __shared__ uint16_t Vs[64*72];       // [c][j]
  __shared__ uint16_t Ps[4][16*72];    // per-wave P scratch

  const int tid  = threadIdx.x;
  const int w    = tid >> 6;
  const int lane = tid & 63;
  const int l15  = lane & 15;
  const int quad = lane >> 4;
  const int b      = blockIdx.x >> 6;
  const int i_base = (blockIdx.x & 63) << 6;

  const uint16_t* Qb = Qg + ((size_t)b*Sn + i_base)*64;
  const uint16_t* Kb = Kg + (size_t)b*Sn*64;
  const uint16_t* Vb = Vg + (size_t)b*Cn*Sn;

  #pragma unroll
  for (int i = 0; i < 2; ++i) {
    const int e   = ((i << 8) + tid) << 3;
    const int row = e >> 6, col = e & 63;
    *(v8s*)(Qs + row*72 + col) = *(const v8s*)(Qb + e);
  }

  float m_r[4], l_r[4];
  v4f o_acc[4];
  #pragma unroll
  for (int r = 0; r < 4; ++r) { m_r[r] = -1e30f; l_r[r] = 0.f; }
  #pragma unroll
  for (int n = 0; n < 4; ++n) o_acc[n] = (v4f){0.f,0.f,0.f,0.f};

  __syncthreads();

  const int arow = (w << 4) + l15;
  v8s aq0 = *(const v8s*)(Qs + arow*72 + (quad << 3));
  v8s aq1 = *(const v8s*)(Qs + arow*72 + 32 + (quad << 3));

  const float SC = 0.18033688011112042f;   // (1/sqrt(64)) * log2(e)

  for (int kt = 0; kt < 64; ++kt) {
    const int jb = kt << 6;
    __syncthreads();
    #pragma unroll
    for (int i = 0; i < 2; ++i) {
      const int e   = ((i << 8) + tid) << 3;
      const int row = e >> 6, col = e & 63;
      *(v8s*)(Ks + row*72 + col) = *(const v8s*)(Kb + jb*64 + e);
      *(v8s*)(Vs + row*72 + col) = *(const v8s*)(Vb + (size_t)row*Sn + jb + col);
    }
    __syncthreads();

    v4f s[4];
    #pragma unroll
    for (int n = 0; n < 4; ++n) {
      const uint16_t* kr = Ks + ((n << 4) + l15)*72;
      v8s b0 = *(const v8s*)(kr + (quad << 3));
      v8s b1 = *(const v8s*)(kr + 32 + (quad << 3));
      v4f t = (v4f){0.f,0.f,0.f,0.f};
      t = MFMA16(aq0, b0, t);
      t = MFMA16(aq1, b1, t);
      s[n] = t;
    }

    float p[4][4];
    float alpha[4];
    #pragma unroll
    for (int r = 0; r < 4; ++r) {
      float mx = fmaxf(fmaxf(s[0][r], s[1][r]), fmaxf(s[2][r], s[3][r]));
      mx = fmaxf(mx, __shfl_xor(mx, 1));
      mx = fmaxf(mx, __shfl_xor(mx, 2));
      mx = fmaxf(mx, __shfl_xor(mx, 4));
      mx = fmaxf(mx, __shfl_xor(mx, 8));
      const float mnew = fmaxf(m_r[r], mx * SC);
      alpha[r] = exp2f(m_r[r] - mnew);
      m_r[r] = mnew;
      float rs = 0.f;
      #pragma unroll
      for (int n = 0; n < 4; ++n) {
        const float pv = exp2f(s[n][r]*SC - mnew);
        p[n][r] = pv;
        rs += pv;
      }
      rs += __shfl_xor(rs, 1);
      rs += __shfl_xor(rs, 2);
      rs += __shfl_xor(rs, 4);
      rs += __shfl_xor(rs, 8);
      l_r[r] = l_r[r]*alpha[r] + rs;
    }

    uint16_t* Pw = Ps[w];
    #pragma unroll
    for (int n = 0; n < 4; ++n)
      #pragma unroll
      for (int r = 0; r < 4; ++r)
        Pw[((quad << 2) + r)*72 + (n << 4) + l15] = f2bf(p[n][r]);

    __asm__ volatile("" ::: "memory");

    v8s ap0 = *(const v8s*)(Pw + l15*72 + (quad << 3));
    v8s ap1 = *(const v8s*)(Pw + l15*72 + 32 + (quad << 3));

    #pragma unroll
    for (int n = 0; n < 4; ++n) {
      v4f o = o_acc[n];
      #pragma unroll
      for (int r = 0; r < 4; ++r) o[r] *= alpha[r];
      const uint16_t* vrp = Vs + ((n << 4) + l15)*72;
      v8s b0 = *(const v8s*)(vrp + (quad << 3));
      v8s b1 = *(const v8s*)(vrp + 32 + (quad << 3));
      o = MFMA16(ap0, b0, o);
      o = MFMA16(ap1, b1, o);
      o_acc[n] = o;
    }
  }

  float inv[4];
  #pragma unroll
  for (int r = 0; r < 4; ++r) inv[r] = 1.f / l_r[r];
  uint16_t* ob = Og + ((size_t)b*Sn + i_base + (w << 4))*64;
  #pragma unroll
  for (int n = 0; n < 4; ++n)
    #pragma unroll
    for (int r = 0; r < 4; ++r)
      ob[((quad << 2) + r)*64 + (n << 4) + l15] = f2bf(o_acc[n][r]*inv[r]);
}

// ---------------- kernel 4: output projection + residual (fp32 out) ----------------
// grid 256 = b*64 + s_tile ; out[b][c][s] = x + Wp @ attn + bp
__global__ __launch_bounds__(256) void proj_res(
    const uint16_t* __restrict__ Ag, const float* __restrict__ wp,
    const float* __restrict__ bp, const float* __restrict__ xg,
    float* __restrict__ out)
{
  __shared__ uint16_t As[64*72];   // [s][c]
  const int tid  = threadIdx.x;
  const int w    = tid >> 6;
  const int lane = tid & 63;
  const int l15  = lane & 15;
  const int quad = lane >> 4;
  const int b      = blockIdx.x >> 6;
  const int s_base = (blockIdx.x & 63) << 6;

  const uint16_t* Ab = Ag + ((size_t)b*Sn + s_base)*64;
  #pragma unroll
  for (int i = 0; i < 2; ++i) {
    const int e   = ((i << 8) + tid) << 3;
    const int row = e >> 6, col = e & 63;
    *(v8s*)(As + row*72 + col) = *(const v8s*)(Ab + e);
  }
  __syncthreads();

  const int arow = (w << 4) + l15;
  v8s ba0 = *(const v8s*)(As + arow*72 + (quad << 3));
  v8s ba1 = *(const v8s*)(As + arow*72 + 32 + (quad << 3));

  #pragma unroll
  for (int mt = 0; mt < 4; ++mt) {
    const float* Wr = wp + ((mt << 4) + l15)*64 + (quad << 3);
    v8s a0 = pack8(*(const float4*)(Wr),      *(const float4*)(Wr + 4));
    v8s a1 = pack8(*(const float4*)(Wr + 32), *(const float4*)(Wr + 36));
    v4f d = (v4f){0.f,0.f,0.f,0.f};
    d = MFMA16(a0, ba0, d);
    d = MFMA16(a1, ba1, d);
    const int s = s_base + (w << 4) + l15;
    #pragma unroll
    for (int r = 0; r < 4; ++r) {
      const int o = (mt << 4) + (quad << 2) + r;
      const size_t idx = ((size_t)b*Cn + o)*Sn + s;
      out[idx] = d[r] + bp[o] + xg[idx];
    }
  }
}

extern "C" void kernel_launch(void* const* d_in, const int* in_sizes, int n_in,
                              void* d_out, int out_size, void* d_ws, size_t ws_size,
                              hipStream_t stream)
{
  const float* x     = (const float*)d_in[0];
  const float* gamma = (const float*)d_in[1];
  const float* beta  = (const float*)d_in[2];
  const float* wq    = (const float*)d_in[3];
  const float* bq    = (const float*)d_in[4];
  const float* wk    = (const float*)d_in[5];
  const float* bk    = (const float*)d_in[6];
  const float* wv    = (const float*)d_in[7];
  const float* bv    = (const float*)d_in[8];
  const float* wp    = (const float*)d_in[9];
  const float* bp    = (const float*)d_in[10];

  float*    stats = (float*)d_ws;                    // 256 floats used
  uint16_t* Qg    = (uint16_t*)d_ws + 1024;          // [B][S][C] bf16 (2 MiB)
  uint16_t* Kg    = Qg + (size_t)Bn*Sn*Cn;           // [B][S][C]
  uint16_t* Vg    = Kg + (size_t)Bn*Sn*Cn;           // [B][C][S]
  uint16_t* Ag    = Vg + (size_t)Bn*Sn*Cn;           // [B][S][C]
  float*    outp  = (float*)d_out;

  gn_stats <<<128, 256, 0, stream>>>(x, stats);
  gn_qkv   <<<256, 256, 0, stream>>>(x, gamma, beta, wq, bq, wk, bk, wv, bv,
                                     stats, Qg, Kg, Vg);
  attn_flash<<<256, 256, 0, stream>>>(Qg, Kg, Vg, Ag);
  proj_res <<<256, 256, 0, stream>>>(Ag, wp, bp, x, outp);
}

// Round 4
// 135.131 us; speedup vs baseline: 1.5067x; 1.5067x over previous
//
#include <hip/hip_runtime.h>
#include <stdint.h>

#define Bn 4
#define Cn 64
#define Sn 4096
#define Gn 32

typedef float v4f __attribute__((ext_vector_type(4)));
typedef short v8s __attribute__((ext_vector_type(8)));

#define MFMA16(a,b,c) __builtin_amdgcn_mfma_f32_16x16x32_bf16((a),(b),(c),0,0,0)

__device__ __forceinline__ float bf2f(uint16_t u){
  union { uint32_t i; float f; } x; x.i = ((uint32_t)u) << 16; return x.f;
}
__device__ __forceinline__ uint16_t f2bf(float f){
  union { float f; uint32_t i; } x; x.f = f;
  uint32_t r = x.i + 0x7fffu + ((x.i >> 16) & 1u);
  return (uint16_t)(r >> 16);
}
__device__ __forceinline__ v8s pack8(float4 a, float4 b){
  v8s r;
  r[0]=(short)f2bf(a.x); r[1]=(short)f2bf(a.y); r[2]=(short)f2bf(a.z); r[3]=(short)f2bf(a.w);
  r[4]=(short)f2bf(b.x); r[5]=(short)f2bf(b.y); r[6]=(short)f2bf(b.z); r[7]=(short)f2bf(b.w);
  return r;
}

// ---------------- kernel 1: GroupNorm stats (mean, rstd) ----------------
__global__ __launch_bounds__(256) void gn_stats(const float* __restrict__ x,
                                                float* __restrict__ stats)
{
  const int tid = threadIdx.x;
  const float* base = x + (size_t)blockIdx.x * 8192;
  float sum = 0.f, sq = 0.f;
  #pragma unroll
  for (int i = 0; i < 8; ++i) {
    float4 v = *(const float4*)(base + ((i << 8) + tid)*4);
    sum += v.x + v.y + v.z + v.w;
    sq  += v.x*v.x + v.y*v.y + v.z*v.z + v.w*v.w;
  }
  #pragma unroll
  for (int off = 1; off < 64; off <<= 1) {
    sum += __shfl_xor(sum, off);
    sq  += __shfl_xor(sq, off);
  }
  __shared__ float red[8];
  const int w = tid >> 6;
  if ((tid & 63) == 0) { red[w] = sum; red[4+w] = sq; }
  __syncthreads();
  if (tid == 0) {
    float s = red[0]+red[1]+red[2]+red[3];
    float q = red[4]+red[5]+red[6]+red[7];
    float mean = s * (1.f/8192.f);
    float var  = q * (1.f/8192.f) - mean*mean;
    stats[blockIdx.x]       = mean;
    stats[128 + blockIdx.x] = rsqrtf(fmaxf(var, 0.f) + 1e-5f);
  }
}

// ---------------- kernel 2: normalize + QKV projection ----------------
__global__ __launch_bounds__(256) void gn_qkv(
    const float* __restrict__ xg, const float* __restrict__ gamma,
    const float* __restrict__ beta,
    const float* __restrict__ wq, const float* __restrict__ bq,
    const float* __restrict__ wk, const float* __restrict__ bk,
    const float* __restrict__ wv, const float* __restrict__ bv,
    const float* __restrict__ stats,
    uint16_t* __restrict__ Qg, uint16_t* __restrict__ Kg, uint16_t* __restrict__ Vg)
{
  __shared__ uint16_t Hs[64*72];   // [s][c] bf16, pad 72
  const int tid  = threadIdx.x;
  const int w    = tid >> 6;
  const int lane = tid & 63;
  const int l15  = lane & 15;
  const int quad = lane >> 4;
  const int b      = blockIdx.x >> 6;
  const int s_base = (blockIdx.x & 63) << 6;

  {
    const int c = lane;
    const int g = c >> 1;
    const float mean = stats[b*Gn + g];
    const float rstd = stats[128 + b*Gn + g];
    const float ga = gamma[c], be = beta[c];
    const float* xr = xg + ((size_t)b*Cn + c)*Sn + s_base + (w << 4);
    #pragma unroll
    for (int j = 0; j < 16; j += 4) {
      float4 v = *(const float4*)(xr + j);
      const int srow = (w << 4) + j;
      Hs[(srow+0)*72 + c] = f2bf((v.x - mean)*rstd*ga + be);
      Hs[(srow+1)*72 + c] = f2bf((v.y - mean)*rstd*ga + be);
      Hs[(srow+2)*72 + c] = f2bf((v.z - mean)*rstd*ga + be);
      Hs[(srow+3)*72 + c] = f2bf((v.w - mean)*rstd*ga + be);
    }
  }
  __syncthreads();

  const int brow = (w << 4) + l15;
  v8s bh0 = *(const v8s*)(Hs + brow*72 + (quad << 3));
  v8s bh1 = *(const v8s*)(Hs + brow*72 + 32 + (quad << 3));

  const float* Ws[3] = {wq, wk, wv};
  const float* Bs[3] = {bq, bk, bv};
  #pragma unroll
  for (int ot = 0; ot < 12; ++ot) {
    const int wsel = ot >> 2;
    const int o16  = (ot & 3) << 4;
    const float* Wr = Ws[wsel] + (o16 + l15)*64 + (quad << 3);
    v8s a0 = pack8(*(const float4*)(Wr),      *(const float4*)(Wr + 4));
    v8s a1 = pack8(*(const float4*)(Wr + 32), *(const float4*)(Wr + 36));
    v4f d = (v4f){0.f,0.f,0.f,0.f};
    d = MFMA16(a0, bh0, d);
    d = MFMA16(a1, bh1, d);
    const int s = s_base + (w << 4) + l15;
    #pragma unroll
    for (int r = 0; r < 4; ++r) {
      const int o = o16 + (quad << 2) + r;
      const float val = d[r] + Bs[wsel][o];
      if (wsel == 0)      Qg[((size_t)b*Sn + s)*64 + o] = f2bf(val);
      else if (wsel == 1) Kg[((size_t)b*Sn + s)*64 + o] = f2bf(val);
      else                Vg[((size_t)b*Cn + o)*Sn + s] = f2bf(val);
    }
  }
}

// ---------------- kernel 3: flash attention, split-K x4, fixed-max softmax ----
// grid 1024: bx = ((b*64 + qt)*4 + split); block 256 = 4 waves x 16 query rows.
// Each block: 64 queries x keys [split*1024, +1024). Partials: O bf16, l fp32.
__global__ __launch_bounds__(256) void attn_split(
    const uint16_t* __restrict__ Qg, const uint16_t* __restrict__ Kg,
    const uint16_t* __restrict__ Vg,
    uint16_t* __restrict__ Opart, float* __restrict__ lpart)
{
  __shared__ uint16_t Qs[64*72];       // [i][c]
  __shared__ uint16_t Ks[64*72];       // [j][c]
  __shared__ uint16_t Vs[64*72];       // [c][j]
  __shared__ uint16_t Ps[4][16*72];    // per-wave P scratch

  const int tid  = threadIdx.x;
  const int w    = tid >> 6;
  const int lane = tid & 63;
  const int l15  = lane & 15;
  const int quad = lane >> 4;
  const int bx    = blockIdx.x;
  const int split = bx & 3;
  const int qt    = (bx >> 2) & 63;
  const int b     = bx >> 8;
  const int i_base = qt << 6;
  const int j0     = split << 10;

  const uint16_t* Qb = Qg + ((size_t)b*Sn + i_base)*64;
  const uint16_t* Kb = Kg + (size_t)b*Sn*64;
  const uint16_t* Vb = Vg + (size_t)b*Cn*Sn;

  #pragma unroll
  for (int i = 0; i < 2; ++i) {
    const int e   = ((i << 8) + tid) << 3;
    const int row = e >> 6, col = e & 63;
    *(v8s*)(Qs + row*72 + col) = *(const v8s*)(Qb + e);
  }

  float lsum[4];
  v4f o_acc[4];
  #pragma unroll
  for (int r = 0; r < 4; ++r) lsum[r] = 0.f;
  #pragma unroll
  for (int n = 0; n < 4; ++n) o_acc[n] = (v4f){0.f,0.f,0.f,0.f};

  __syncthreads();

  const int arow = (w << 4) + l15;
  v8s aq0 = *(const v8s*)(Qs + arow*72 + (quad << 3));
  v8s aq1 = *(const v8s*)(Qs + arow*72 + 32 + (quad << 3));

  const float SC = 0.18033688011112042f;   // (1/sqrt(64)) * log2(e)

  for (int kt = 0; kt < 16; ++kt) {
    const int jb = j0 + (kt << 6);
    __syncthreads();
    #pragma unroll
    for (int i = 0; i < 2; ++i) {
      const int e   = ((i << 8) + tid) << 3;
      const int row = e >> 6, col = e & 63;
      *(v8s*)(Ks + row*72 + col) = *(const v8s*)(Kb + jb*64 + e);
      *(v8s*)(Vs + row*72 + col) = *(const v8s*)(Vb + (size_t)row*Sn + jb + col);
    }
    __syncthreads();

    // S = Q K^T
    v4f s[4];
    #pragma unroll
    for (int n = 0; n < 4; ++n) {
      const uint16_t* kr = Ks + ((n << 4) + l15)*72;
      v8s b0 = *(const v8s*)(kr + (quad << 3));
      v8s b1 = *(const v8s*)(kr + 32 + (quad << 3));
      v4f t = (v4f){0.f,0.f,0.f,0.f};
      t = MFMA16(aq0, b0, t);
      t = MFMA16(aq1, b1, t);
      s[n] = t;
    }

    // fixed-max softmax numerator: p = 2^(s*SC); defer l reduction
    uint16_t* Pw = Ps[w];
    #pragma unroll
    for (int n = 0; n < 4; ++n) {
      #pragma unroll
      for (int r = 0; r < 4; ++r) {
        const float pv = __builtin_amdgcn_exp2f(s[n][r]*SC);
        lsum[r] += pv;
        Pw[((quad << 2) + r)*72 + (n << 4) + l15] = f2bf(pv);
      }
    }

    __asm__ volatile("" ::: "memory");

    v8s ap0 = *(const v8s*)(Pw + l15*72 + (quad << 3));
    v8s ap1 = *(const v8s*)(Pw + l15*72 + 32 + (quad << 3));

    // O += P V^T (no rescale)
    #pragma unroll
    for (int n = 0; n < 4; ++n) {
      const uint16_t* vrp = Vs + ((n << 4) + l15)*72;
      v8s b0 = *(const v8s*)(vrp + (quad << 3));
      v8s b1 = *(const v8s*)(vrp + 32 + (quad << 3));
      v4f o = o_acc[n];
      o = MFMA16(ap0, b0, o);
      o = MFMA16(ap1, b1, o);
      o_acc[n] = o;
    }
  }

  // reduce l over the 16 lanes holding each row's 64 columns (once, not per tile)
  #pragma unroll
  for (int r = 0; r < 4; ++r) {
    lsum[r] += __shfl_xor(lsum[r], 1);
    lsum[r] += __shfl_xor(lsum[r], 2);
    lsum[r] += __shfl_xor(lsum[r], 4);
    lsum[r] += __shfl_xor(lsum[r], 8);
  }

  uint16_t* Ob = Opart + (size_t)bx*4096 + (w << 4)*64;
  float*    lp = lpart + bx*64 + (w << 4);
  #pragma unroll
  for (int n = 0; n < 4; ++n)
    #pragma unroll
    for (int r = 0; r < 4; ++r)
      Ob[((quad << 2) + r)*64 + (n << 4) + l15] = f2bf(o_acc[n][r]);
  if (l15 == 0) {
    #pragma unroll
    for (int r = 0; r < 4; ++r) lp[(quad << 2) + r] = lsum[r];
  }
}

// ---------------- kernel 4: merge splits + output projection + residual ------
// grid 256 = b*64 + qt ; out[b][c][s] = x + Wp @ (sum_splits O / sum_splits l) + bp
__global__ __launch_bounds__(256) void proj_res(
    const uint16_t* __restrict__ Opart, const float* __restrict__ lpart,
    const float* __restrict__ wp, const float* __restrict__ bp,
    const float* __restrict__ xg, float* __restrict__ out)
{
  __shared__ uint16_t As[64*72];   // merged attention tile [s][c]
  const int tid  = threadIdx.x;
  const int w    = tid >> 6;
  const int lane = tid & 63;
  const int l15  = lane & 15;
  const int quad = lane >> 4;
  const int bx   = blockIdx.x;
  const int b      = bx >> 6;
  const int s_base = (bx & 63) << 6;

  const uint16_t* po = Opart + (size_t)bx*4*4096;
  const float*    pl = lpart + bx*4*64;

  #pragma unroll
  for (int i = 0; i < 2; ++i) {
    const int e   = ((i << 8) + tid) << 3;
    const int row = e >> 6, col = e & 63;
    const float linv = 1.f / (pl[row] + pl[64+row] + pl[128+row] + pl[192+row]);
    float acc[8] = {0,0,0,0,0,0,0,0};
    #pragma unroll
    for (int sp = 0; sp < 4; ++sp) {
      v8s o = *(const v8s*)(po + sp*4096 + e);
      #pragma unroll
      for (int j = 0; j < 8; ++j) acc[j] += bf2f((uint16_t)o[j]);
    }
    v8s a;
    #pragma unroll
    for (int j = 0; j < 8; ++j) a[j] = (short)f2bf(acc[j]*linv);
    *(v8s*)(As + row*72 + col) = a;
  }
  __syncthreads();

  const int arow = (w << 4) + l15;
  v8s ba0 = *(const v8s*)(As + arow*72 + (quad << 3));
  v8s ba1 = *(const v8s*)(As + arow*72 + 32 + (quad << 3));

  #pragma unroll
  for (int mt = 0; mt < 4; ++mt) {
    const float* Wr = wp + ((mt << 4) + l15)*64 + (quad << 3);
    v8s a0 = pack8(*(const float4*)(Wr),      *(const float4*)(Wr + 4));
    v8s a1 = pack8(*(const float4*)(Wr + 32), *(const float4*)(Wr + 36));
    v4f d = (v4f){0.f,0.f,0.f,0.f};
    d = MFMA16(a0, ba0, d);
    d = MFMA16(a1, ba1, d);
    const int s = s_base + (w << 4) + l15;
    #pragma unroll
    for (int r = 0; r < 4; ++r) {
      const int o = (mt << 4) + (quad << 2) + r;
      const size_t idx = ((size_t)b*Cn + o)*Sn + s;
      out[idx] = d[r] + bp[o] + xg[idx];
    }
  }
}

extern "C" void kernel_launch(void* const* d_in, const int* in_sizes, int n_in,
                              void* d_out, int out_size, void* d_ws, size_t ws_size,
                              hipStream_t stream)
{
  const float* x     = (const float*)d_in[0];
  const float* gamma = (const float*)d_in[1];
  const float* beta  = (const float*)d_in[2];
  const float* wq    = (const float*)d_in[3];
  const float* bq    = (const float*)d_in[4];
  const float* wk    = (const float*)d_in[5];
  const float* bk    = (const float*)d_in[6];
  const float* wv    = (const float*)d_in[7];
  const float* bv    = (const float*)d_in[8];
  const float* wp    = (const float*)d_in[9];
  const float* bp    = (const float*)d_in[10];

  float*    stats = (float*)d_ws;                        // 256 floats
  uint16_t* Qg    = (uint16_t*)d_ws + 1024;              // [B][S][C] bf16 (2 MiB)
  uint16_t* Kg    = Qg + (size_t)Bn*Sn*Cn;               // [B][S][C]
  uint16_t* Vg    = Kg + (size_t)Bn*Sn*Cn;               // [B][C][S]
  uint16_t* Opart = Vg + (size_t)Bn*Sn*Cn;               // 1024 x 64 x 64 bf16 (8 MiB)
  float*    lpart = (float*)(Opart + (size_t)1024*4096); // 1024 x 64 f32 (256 KiB)
  float*    outp  = (float*)d_out;

  gn_stats  <<<128, 256, 0, stream>>>(x, stats);
  gn_qkv    <<<256, 256, 0, stream>>>(x, gamma, beta, wq, bq, wk, bk, wv, bv,
                                      stats, Qg, Kg, Vg);
  attn_split<<<1024, 256, 0, stream>>>(Qg, Kg, Vg, Opart, lpart);
  proj_res  <<<256, 256, 0, stream>>>(Opart, lpart, wp, bp, x, outp);
}

// Round 5
// 132.083 us; speedup vs baseline: 1.5414x; 1.0231x over previous
//
#include <hip/hip_runtime.h>
#include <stdint.h>

#define Bn 4
#define Cn 64
#define Sn 4096
#define Gn 32

typedef float v4f __attribute__((ext_vector_type(4)));
typedef short v8s __attribute__((ext_vector_type(8)));
typedef short v4s __attribute__((ext_vector_type(4)));

#define MFMA16(a,b,c) __builtin_amdgcn_mfma_f32_16x16x32_bf16((a),(b),(c),0,0,0)

__device__ __forceinline__ float bf2f(uint16_t u){
  union { uint32_t i; float f; } x; x.i = ((uint32_t)u) << 16; return x.f;
}
__device__ __forceinline__ uint16_t f2bf(float f){
  union { float f; uint32_t i; } x; x.f = f;
  uint32_t r = x.i + 0x7fffu + ((x.i >> 16) & 1u);
  return (uint16_t)(r >> 16);
}
__device__ __forceinline__ v8s pack8(float4 a, float4 b){
  v8s r;
  r[0]=(short)f2bf(a.x); r[1]=(short)f2bf(a.y); r[2]=(short)f2bf(a.z); r[3]=(short)f2bf(a.w);
  r[4]=(short)f2bf(b.x); r[5]=(short)f2bf(b.y); r[6]=(short)f2bf(b.z); r[7]=(short)f2bf(b.w);
  return r;
}

// ---------------- kernel 1: GroupNorm stats (mean, rstd) ----------------
// grid 128 = b*32+g ; each block reduces 2 channels x 4096 spatial (fp32)
__global__ __launch_bounds__(256) void gn_stats(const float* __restrict__ x,
                                                float* __restrict__ stats)
{
  const int tid = threadIdx.x;
  const float* base = x + (size_t)blockIdx.x * 8192;
  float sum = 0.f, sq = 0.f;
  #pragma unroll
  for (int i = 0; i < 8; ++i) {
    float4 v = *(const float4*)(base + ((i << 8) + tid)*4);
    sum += v.x + v.y + v.z + v.w;
    sq  += v.x*v.x + v.y*v.y + v.z*v.z + v.w*v.w;
  }
  #pragma unroll
  for (int off = 1; off < 64; off <<= 1) {
    sum += __shfl_xor(sum, off);
    sq  += __shfl_xor(sq, off);
  }
  __shared__ float red[8];
  const int w = tid >> 6;
  if ((tid & 63) == 0) { red[w] = sum; red[4+w] = sq; }
  __syncthreads();
  if (tid == 0) {
    float s = red[0]+red[1]+red[2]+red[3];
    float q = red[4]+red[5]+red[6]+red[7];
    float mean = s * (1.f/8192.f);
    float var  = q * (1.f/8192.f) - mean*mean;
    stats[blockIdx.x]       = mean;
    stats[128 + blockIdx.x] = rsqrtf(fmaxf(var, 0.f) + 1e-5f);
  }
}

// ---------------- kernel 2: normalize + QKV projection (16-row tiles) --------
// grid 1024: bx = b*256 + st, s_base = st*16. Q,K out [b][s][c]; V out [b][c][s]
__global__ __launch_bounds__(256) void gn_qkv(
    const float* __restrict__ xg, const float* __restrict__ gamma,
    const float* __restrict__ beta,
    const float* __restrict__ wq, const float* __restrict__ bq,
    const float* __restrict__ wk, const float* __restrict__ bk,
    const float* __restrict__ wv, const float* __restrict__ bv,
    const float* __restrict__ stats,
    uint16_t* __restrict__ Qg, uint16_t* __restrict__ Kg, uint16_t* __restrict__ Vg)
{
  __shared__ uint16_t Hs[16*72];   // [s][c] bf16, pad 72
  const int tid  = threadIdx.x;
  const int w    = tid >> 6;
  const int lane = tid & 63;
  const int l15  = lane & 15;
  const int quad = lane >> 4;
  const int b      = blockIdx.x >> 8;
  const int s_base = (blockIdx.x & 255) << 4;

  { // thread owns channel c = lane, 4 spatial rows (w*4..w*4+3)
    const int c = lane;
    const int g = c >> 1;
    const float mean = stats[b*Gn + g];
    const float rstd = stats[128 + b*Gn + g];
    const float ga = gamma[c], be = beta[c];
    float4 v = *(const float4*)(xg + ((size_t)b*Cn + c)*Sn + s_base + (w << 2));
    const int r0 = w << 2;
    Hs[(r0+0)*72 + c] = f2bf((v.x - mean)*rstd*ga + be);
    Hs[(r0+1)*72 + c] = f2bf((v.y - mean)*rstd*ga + be);
    Hs[(r0+2)*72 + c] = f2bf((v.z - mean)*rstd*ga + be);
    Hs[(r0+3)*72 + c] = f2bf((v.w - mean)*rstd*ga + be);
  }
  __syncthreads();

  // B fragments: n = spatial col (16 rows of this block), k = channel
  v8s bh0 = *(const v8s*)(Hs + l15*72 + (quad << 3));
  v8s bh1 = *(const v8s*)(Hs + l15*72 + 32 + (quad << 3));

  #pragma unroll
  for (int t = 0; t < 3; ++t) {
    const int ot   = w*3 + t;          // 0..11 across the 4 waves
    const int wsel = ot >> 2;
    const int o16  = (ot & 3) << 4;
    const float* Wsel = (wsel == 0) ? wq : (wsel == 1) ? wk : wv;
    const float* Bsel = (wsel == 0) ? bq : (wsel == 1) ? bk : bv;
    const float* Wr = Wsel + (o16 + l15)*64 + (quad << 3);
    v8s a0 = pack8(*(const float4*)(Wr),      *(const float4*)(Wr + 4));
    v8s a1 = pack8(*(const float4*)(Wr + 32), *(const float4*)(Wr + 36));
    v4f d = (v4f){0.f,0.f,0.f,0.f};
    d = MFMA16(a0, bh0, d);
    d = MFMA16(a1, bh1, d);
    const int s = s_base + l15;
    if (wsel <= 1) {           // Q/K: pack 4 consecutive channels -> one 8B store
      v4s qv;
      #pragma unroll
      for (int r = 0; r < 4; ++r)
        qv[r] = (short)f2bf(d[r] + Bsel[o16 + (quad << 2) + r]);
      uint16_t* dst = (wsel == 0 ? Qg : Kg) + ((size_t)b*Sn + s)*64 + o16 + (quad << 2);
      *(v4s*)dst = qv;
    } else {                   // V: [c][s] layout, consecutive lanes = consecutive s
      #pragma unroll
      for (int r = 0; r < 4; ++r) {
        const int o = o16 + (quad << 2) + r;
        Vg[((size_t)b*Cn + o)*Sn + s] = f2bf(d[r] + Bsel[o]);
      }
    }
  }
}

// ---------------- kernel 3: attention, split-K x4, register-prefetch ---------
// grid 1024: bx = ((b*64 + qt)*4 + split); block 256 = 4 waves x 16 query rows.
// Per tile: prefetch next K/V to regs BEFORE compute; barriers only around the
// regs->LDS writeback, so global latency overlaps MFMA.
__global__ __launch_bounds__(256) void attn_split(
    const uint16_t* __restrict__ Qg, const uint16_t* __restrict__ Kg,
    const uint16_t* __restrict__ Vg,
    uint16_t* __restrict__ Opart, float* __restrict__ lpart)
{
  __shared__ uint16_t Ks[64*72];       // [j][c]
  __shared__ uint16_t Vs[64*72];       // [c][j]
  __shared__ uint16_t Ps[4][16*72];    // per-wave P scratch

  const int tid  = threadIdx.x;
  const int w    = tid >> 6;
  const int lane = tid & 63;
  const int l15  = lane & 15;
  const int quad = lane >> 4;
  const int bx    = blockIdx.x;
  const int split = bx & 3;
  const int qt    = (bx >> 2) & 63;
  const int b     = bx >> 8;
  const int i_base = qt << 6;
  const int j0     = split << 10;

  const uint16_t* Qb = Qg + ((size_t)b*Sn + i_base)*64;
  const uint16_t* Kb = Kg + (size_t)b*Sn*64;
  const uint16_t* Vb = Vg + (size_t)b*Cn*Sn;

  // Q fragments straight from global (once)
  const int arow = (w << 4) + l15;
  v8s aq0 = *(const v8s*)(Qb + arow*64 + (quad << 3));
  v8s aq1 = *(const v8s*)(Qb + arow*64 + 32 + (quad << 3));

  // staging geometry: thread t covers elems e=t*8 (+2048), row=e>>6, col=e&63
  const int e0 = tid << 3,        r0 = e0 >> 6, c0 = e0 & 63;
  const int e1 = (256 + tid) << 3, r1 = e1 >> 6, c1 = e1 & 63;

  // stage tile 0
  *(v8s*)(Ks + r0*72 + c0) = *(const v8s*)(Kb + j0*64 + e0);
  *(v8s*)(Ks + r1*72 + c1) = *(const v8s*)(Kb + j0*64 + e1);
  *(v8s*)(Vs + r0*72 + c0) = *(const v8s*)(Vb + (size_t)r0*Sn + j0 + c0);
  *(v8s*)(Vs + r1*72 + c1) = *(const v8s*)(Vb + (size_t)r1*Sn + j0 + c1);

  float lsum[4];
  v4f o_acc[4];
  #pragma unroll
  for (int r = 0; r < 4; ++r) lsum[r] = 0.f;
  #pragma unroll
  for (int n = 0; n < 4; ++n) o_acc[n] = (v4f){0.f,0.f,0.f,0.f};

  __syncthreads();

  const float SC = 0.18033688011112042f;   // (1/sqrt(64)) * log2(e)

  for (int kt = 0; kt < 16; ++kt) {
    // prefetch next tile into registers (latency overlaps the compute below)
    v8s kp0, kp1, vp0, vp1;
    if (kt < 15) {
      const int jb = j0 + ((kt + 1) << 6);
      kp0 = *(const v8s*)(Kb + jb*64 + e0);
      kp1 = *(const v8s*)(Kb + jb*64 + e1);
      vp0 = *(const v8s*)(Vb + (size_t)r0*Sn + jb + c0);
      vp1 = *(const v8s*)(Vb + (size_t)r1*Sn + jb + c1);
    }

    // S = Q K^T (16 query rows x 64 keys per wave)
    v4f s[4];
    #pragma unroll
    for (int n = 0; n < 4; ++n) {
      const uint16_t* kr = Ks + ((n << 4) + l15)*72;
      v8s b0 = *(const v8s*)(kr + (quad << 3));
      v8s b1 = *(const v8s*)(kr + 32 + (quad << 3));
      v4f t = (v4f){0.f,0.f,0.f,0.f};
      t = MFMA16(aq0, b0, t);
      t = MFMA16(aq1, b1, t);
      s[n] = t;
    }

    // fixed-max softmax numerator p = 2^(s*SC); l reduction deferred to end
    uint16_t* Pw = Ps[w];
    #pragma unroll
    for (int n = 0; n < 4; ++n) {
      #pragma unroll
      for (int r = 0; r < 4; ++r) {
        const float pv = __builtin_amdgcn_exp2f(s[n][r]*SC);
        lsum[r] += pv;
        Pw[((quad << 2) + r)*72 + (n << 4) + l15] = f2bf(pv);
      }
    }

    __asm__ volatile("" ::: "memory");

    v8s ap0 = *(const v8s*)(Pw + l15*72 + (quad << 3));
    v8s ap1 = *(const v8s*)(Pw + l15*72 + 32 + (quad << 3));

    // O += P V^T
    #pragma unroll
    for (int n = 0; n < 4; ++n) {
      const uint16_t* vrp = Vs + ((n << 4) + l15)*72;
      v8s b0 = *(const v8s*)(vrp + (quad << 3));
      v8s b1 = *(const v8s*)(vrp + 32 + (quad << 3));
      v4f o = o_acc[n];
      o = MFMA16(ap0, b0, o);
      o = MFMA16(ap1, b1, o);
      o_acc[n] = o;
    }

    __syncthreads();            // all waves done reading Ks/Vs
    if (kt < 15) {
      *(v8s*)(Ks + r0*72 + c0) = kp0;
      *(v8s*)(Ks + r1*72 + c1) = kp1;
      *(v8s*)(Vs + r0*72 + c0) = vp0;
      *(v8s*)(Vs + r1*72 + c1) = vp1;
    }
    __syncthreads();            // writeback visible
  }

  // reduce l across the 16 lanes holding each row (once)
  #pragma unroll
  for (int r = 0; r < 4; ++r) {
    lsum[r] += __shfl_xor(lsum[r], 1);
    lsum[r] += __shfl_xor(lsum[r], 2);
    lsum[r] += __shfl_xor(lsum[r], 4);
    lsum[r] += __shfl_xor(lsum[r], 8);
  }

  uint16_t* Ob = Opart + (size_t)bx*4096 + (w << 4)*64;
  float*    lp = lpart + bx*64 + (w << 4);
  #pragma unroll
  for (int n = 0; n < 4; ++n)
    #pragma unroll
    for (int r = 0; r < 4; ++r)
      Ob[((quad << 2) + r)*64 + (n << 4) + l15] = f2bf(o_acc[n][r]);
  if (l15 == 0) {
    #pragma unroll
    for (int r = 0; r < 4; ++r) lp[(quad << 2) + r] = lsum[r];
  }
}

// ---------------- kernel 4: merge splits + projection + residual (16-row) ----
// grid 1024: bx = b*256 + st; s rows [st*16, +16). out[b][c][s] = x + Wp@A + bp
__global__ __launch_bounds__(256) void proj_res(
    const uint16_t* __restrict__ Opart, const float* __restrict__ lpart,
    const float* __restrict__ wp, const float* __restrict__ bp,
    const float* __restrict__ xg, float* __restrict__ out)
{
  __shared__ uint16_t As[16*72];   // merged attention subtile [s][c]
  const int tid  = threadIdx.x;
  const int w    = tid >> 6;
  const int lane = tid & 63;
  const int l15  = lane & 15;
  const int quad = lane >> 4;
  const int b      = blockIdx.x >> 8;
  const int st     = blockIdx.x & 255;
  const int qt     = st >> 2;
  const int sub    = st & 3;
  const int s_base = st << 4;

  const uint16_t* po = Opart + (size_t)((b*64 + qt)*4)*4096 + (sub << 4)*64;
  const float*    pl = lpart + ((b*64 + qt)*4)*64 + (sub << 4);

  { // merge: thread t -> 4 elems, row = t>>4, col = (t&15)*4
    const int e = tid << 2, row = tid >> 4, col = (tid & 15) << 2;
    const float linv = 1.f / (pl[row] + pl[64+row] + pl[128+row] + pl[192+row]);
    float acc[4] = {0.f,0.f,0.f,0.f};
    #pragma unroll
    for (int sp = 0; sp < 4; ++sp) {
      v4s o = *(const v4s*)(po + sp*4096 + e);
      #pragma unroll
      for (int j = 0; j < 4; ++j) acc[j] += bf2f((uint16_t)o[j]);
    }
    v4s a;
    #pragma unroll
    for (int j = 0; j < 4; ++j) a[j] = (short)f2bf(acc[j]*linv);
    *(v4s*)(As + row*72 + col) = a;
  }
  __syncthreads();

  v8s ba0 = *(const v8s*)(As + l15*72 + (quad << 3));
  v8s ba1 = *(const v8s*)(As + l15*72 + 32 + (quad << 3));

  // wave w computes output channels [w*16, +16)
  const float* Wr = wp + ((w << 4) + l15)*64 + (quad << 3);
  v8s a0 = pack8(*(const float4*)(Wr),      *(const float4*)(Wr + 4));
  v8s a1 = pack8(*(const float4*)(Wr + 32), *(const float4*)(Wr + 36));
  v4f d = (v4f){0.f,0.f,0.f,0.f};
  d = MFMA16(a0, ba0, d);
  d = MFMA16(a1, ba1, d);
  const int s = s_base + l15;
  #pragma unroll
  for (int r = 0; r < 4; ++r) {
    const int o = (w << 4) + (quad << 2) + r;
    const size_t idx = ((size_t)b*Cn + o)*Sn + s;
    out[idx] = d[r] + bp[o] + xg[idx];
  }
}

extern "C" void kernel_launch(void* const* d_in, const int* in_sizes, int n_in,
                              void* d_out, int out_size, void* d_ws, size_t ws_size,
                              hipStream_t stream)
{
  const float* x     = (const float*)d_in[0];
  const float* gamma = (const float*)d_in[1];
  const float* beta  = (const float*)d_in[2];
  const float* wq    = (const float*)d_in[3];
  const float* bq    = (const float*)d_in[4];
  const float* wk    = (const float*)d_in[5];
  const float* bk    = (const float*)d_in[6];
  const float* wv    = (const float*)d_in[7];
  const float* bv    = (const float*)d_in[8];
  const float* wp    = (const float*)d_in[9];
  const float* bp    = (const float*)d_in[10];

  float*    stats = (float*)d_ws;                        // 256 floats
  uint16_t* Qg    = (uint16_t*)d_ws + 1024;              // [B][S][C] bf16 (2 MiB)
  uint16_t* Kg    = Qg + (size_t)Bn*Sn*Cn;               // [B][S][C]
  uint16_t* Vg    = Kg + (size_t)Bn*Sn*Cn;               // [B][C][S]
  uint16_t* Opart = Vg + (size_t)Bn*Sn*Cn;               // 1024 x 64 x 64 bf16 (8 MiB)
  float*    lpart = (float*)(Opart + (size_t)1024*4096); // 1024 x 64 f32 (256 KiB)
  float*    outp  = (float*)d_out;

  gn_stats  <<<128, 256, 0, stream>>>(x, stats);
  gn_qkv    <<<1024, 256, 0, stream>>>(x, gamma, beta, wq, bq, wk, bk, wv, bv,
                                       stats, Qg, Kg, Vg);
  attn_split<<<1024, 256, 0, stream>>>(Qg, Kg, Vg, Opart, lpart);
  proj_res  <<<1024, 256, 0, stream>>>(Opart, lpart, wp, bp, x, outp);
}